// Round 9
// baseline (15095.401 us; speedup 1.0000x reference)
//
#include <hip/hip_runtime.h>
#include <hip/hip_bf16.h>

// ---------------------------------------------------------------------------
// Strict f64 squared distance matching numpy float64:
//   d = ((dx*dx + dy*dy) + dz*dz), every op individually rounded, no FMA.
// ---------------------------------------------------------------------------
__device__ __forceinline__ double dist2d(float x, float y, float z,
                                         double px, double py, double pz) {
    double dx = __dsub_rn((double)x, px);
    double dy = __dsub_rn((double)y, py);
    double dz = __dsub_rn((double)z, pz);
    double a  = __dmul_rn(dx, dx);
    double b  = __dmul_rn(dy, dy);
    double c  = __dmul_rn(dz, dz);
    return __dadd_rn(__dadd_rn(a, b), c);
}

__device__ __forceinline__ int lo32d(double v) {
    return (int)(__double_as_longlong(v) & 0xFFFFFFFFLL);
}
__device__ __forceinline__ int hi32d(double v) {
    return (int)(((unsigned long long)__double_as_longlong(v)) >> 32);
}
__device__ __forceinline__ double mk_f64(int lo, int hi) {
    return __longlong_as_double(((long long)(unsigned)hi << 32) | (unsigned)lo);
}

template <int CTRL>
__device__ __forceinline__ int dpp_i(int v) {
    return __builtin_amdgcn_update_dpp(v, v, CTRL, 0xF, 0xF, false);
}
template <int CTRL>
__device__ __forceinline__ float dpp_f(float v) {
    return __int_as_float(
        __builtin_amdgcn_update_dpp(__float_as_int(v), __float_as_int(v),
                                    CTRL, 0xF, 0xF, false));
}
template <int CTRL>
__device__ __forceinline__ double dpp_f64_keep(double v) {
    long long b = __double_as_longlong(v);
    int lo = (int)(b & 0xFFFFFFFFLL);
    int hi = (int)(((unsigned long long)b) >> 32);
    int lo2 = __builtin_amdgcn_update_dpp(lo, lo, CTRL, 0xF, 0xF, false);
    int hi2 = __builtin_amdgcn_update_dpp(hi, hi, CTRL, 0xF, 0xF, false);
    return __longlong_as_double(((long long)(unsigned)hi2 << 32) | (unsigned)lo2);
}

// Lane 63 holds the full 64-lane reduction after these.
__device__ __forceinline__ int wave_max_i32(int v) {
    v = max(v, dpp_i<0x111>(v)); v = max(v, dpp_i<0x112>(v));
    v = max(v, dpp_i<0x114>(v)); v = max(v, dpp_i<0x118>(v));
    v = max(v, dpp_i<0x142>(v)); v = max(v, dpp_i<0x143>(v));
    return v;
}
__device__ __forceinline__ int wave_min_i32(int v) {
    v = min(v, dpp_i<0x111>(v)); v = min(v, dpp_i<0x112>(v));
    v = min(v, dpp_i<0x114>(v)); v = min(v, dpp_i<0x118>(v));
    v = min(v, dpp_i<0x142>(v)); v = min(v, dpp_i<0x143>(v));
    return v;
}
__device__ __forceinline__ unsigned wave_max_u32(unsigned v) {
    v = max(v, (unsigned)dpp_i<0x111>((int)v));
    v = max(v, (unsigned)dpp_i<0x112>((int)v));
    v = max(v, (unsigned)dpp_i<0x114>((int)v));
    v = max(v, (unsigned)dpp_i<0x118>((int)v));
    v = max(v, (unsigned)dpp_i<0x142>((int)v));
    v = max(v, (unsigned)dpp_i<0x143>((int)v));
    return v;
}
__device__ __forceinline__ float wave_max_f32(float v) {
    v = fmaxf(v, dpp_f<0x111>(v)); v = fmaxf(v, dpp_f<0x112>(v));
    v = fmaxf(v, dpp_f<0x114>(v)); v = fmaxf(v, dpp_f<0x118>(v));
    v = fmaxf(v, dpp_f<0x142>(v)); v = fmaxf(v, dpp_f<0x143>(v));
    return v;
}
__device__ __forceinline__ float wave_min_f32(float v) {
    v = fminf(v, dpp_f<0x111>(v)); v = fminf(v, dpp_f<0x112>(v));
    v = fminf(v, dpp_f<0x114>(v)); v = fminf(v, dpp_f<0x118>(v));
    v = fminf(v, dpp_f<0x142>(v)); v = fminf(v, dpp_f<0x143>(v));
    return v;
}

__device__ __forceinline__ double readlane_f64(double v, int l) {
    long long b = __double_as_longlong(v);
    int lo = __builtin_amdgcn_readlane((int)(b & 0xFFFFFFFFLL), l);
    int hi = __builtin_amdgcn_readlane((int)(((unsigned long long)b) >> 32), l);
    return __longlong_as_double(((long long)(unsigned)hi << 32) | (unsigned)lo);
}
__device__ __forceinline__ float readlane_f32(float v, int l) {
    return __int_as_float(__builtin_amdgcn_readlane(__float_as_int(v), l));
}

__device__ __forceinline__ unsigned part1by2(unsigned v) {
    v = (v * 0x00010001u) & 0xFF0000FFu;
    v = (v * 0x00000101u) & 0x0F00F00Fu;
    v = (v * 0x00000011u) & 0xC30C30C3u;
    v = (v * 0x00000005u) & 0x49249249u;
    return v;
}

// ---------------------------------------------------------------------------
// Spatial sort: one block per batch, bitonic sort of (morton18<<13 | pos).
// Hash quality affects only downstream skip efficiency, never correctness.
// ---------------------------------------------------------------------------
template <int N, int NT>
__global__ __launch_bounds__(NT) void sort_kernel(
    const float* __restrict__ pts, int stride,
    float* __restrict__ perm_xyz,
    int* __restrict__ perm_oi,
    int* __restrict__ pos0s)
{
    __shared__ unsigned arr[N];
    const int batch = blockIdx.x;
    const int tid   = threadIdx.x;
    const float* base = pts + (size_t)batch * N * stride;

    for (int p = tid; p < N; p += NT) {
        const float* r = base + (size_t)p * stride;
        unsigned xi = (unsigned)fminf(fmaxf((r[0] + 4.0f) * 8.0f, 0.0f), 63.0f);
        unsigned yi = (unsigned)fminf(fmaxf((r[1] + 4.0f) * 8.0f, 0.0f), 63.0f);
        unsigned zi = (unsigned)fminf(fmaxf((r[2] + 4.0f) * 8.0f, 0.0f), 63.0f);
        unsigned code = part1by2(xi) | (part1by2(yi) << 1) | (part1by2(zi) << 2);
        arr[p] = (code << 13) | (unsigned)p;
    }
    __syncthreads();

    for (int size = 2; size <= N; size <<= 1) {
        for (int str = size >> 1; str > 0; str >>= 1) {
            for (int t = tid; t < N / 2; t += NT) {
                int i = ((t & ~(str - 1)) << 1) | (t & (str - 1));
                unsigned a = arr[i], b = arr[i | str];
                bool up = ((i & size) == 0);
                if ((a > b) == up) { arr[i] = b; arr[i | str] = a; }
            }
            __syncthreads();
        }
    }

    for (int s = tid; s < N; s += NT) {
        int p = (int)(arr[s] & 0x1FFFu);
        const float* r = base + (size_t)p * stride;
        float* w = perm_xyz + ((size_t)batch * N + s) * 3;
        w[0] = r[0]; w[1] = r[1]; w[2] = r[2];
        perm_oi[(size_t)batch * N + s] = p;
        if (p == 0) pos0s[batch] = s;
    }
}

// ---------------------------------------------------------------------------
// FPS on Morton-sorted points. 256 threads (4 waves, 1/SIMD) per batch.
// Bucket b (64 contiguous sorted points) owned by (wave b&3, slot b>>2);
// lane l of EVERY wave holds the static AABB of bucket l (+l+64 if NB=128).
// Per iteration:
//   1. wave argmax via hi-bits i32 DPP (md>=0 => f64 order == (hi,lo) lex);
//      lo-bits / min-original-index fallbacks only on exact ties (bounded).
//      Winning lane writes its packed partial (bv, oi, x, y, z); ONE barrier.
//   2. cross-wave: 4 partials, 2-step DPP f64 max + bounded min-oi tie.
//   3. BB gate: one point-to-box test per lane screens ALL buckets against
//      thmax[b] (LDS, monotone-stale upper bound of per-point th -> always
//      conservative => exact); 2 ballots -> sgpr fire mask.
//   4. fired buckets only: per-point f32 screen (margin 1.000004, proven)
//      gates strict-f64 md update; holder-gated rescan; dirty thmax refresh
//      every 4th iteration.
// ---------------------------------------------------------------------------
template <int PPT>
__global__ __launch_bounds__(256, 1) void fps_kernel(
    const float* __restrict__ perm_xyz,  // [B][N_IN][3]
    const int* __restrict__ perm_oi,     // [B][N_IN]
    const int* __restrict__ pos0s,       // [B]
    int npoints,
    int* __restrict__ idx_out)           // [B][npoints] (original indices)
{
    constexpr int NW   = 4;
    constexpr int N_IN = PPT * 256;
    constexpr int NB   = N_IN / 64;          // buckets
    constexpr int BPL  = (NB + 63) / 64;     // buckets per lane (1 or 2)

    const int batch = blockIdx.x;
    const int tid   = threadIdx.x;
    const int lane  = tid & 63;
    const int wvu   = __builtin_amdgcn_readfirstlane(tid >> 6);

    const float* base   = perm_xyz + (size_t)batch * N_IN * 3;
    const int*   oibase = perm_oi + (size_t)batch * N_IN;
    int* iout = idx_out + (size_t)batch * npoints;

    __shared__ int   s_part[2][NW][8];  // [bv_lo, bv_hi, oi, x, y, z, pad, pad]
    __shared__ float s_thmax[NB];
    __shared__ float s_bb[NB][6];

    float  cx[PPT], cy[PPT], cz[PPT];
    int    oi_[PPT];
    double md[PPT];
    float  th[PPT];

#pragma unroll
    for (int j = 0; j < PPT; ++j) {
        int s = (j * NW + wvu) * 64 + lane;
        const float* r = base + (size_t)s * 3;
        cx[j] = r[0]; cy[j] = r[1]; cz[j] = r[2];
        oi_[j] = oibase[s];
    }

    // one-time: bucket AABBs
#pragma unroll
    for (int j = 0; j < PPT; ++j) {
        int b = j * NW + wvu;
        float mnx = wave_min_f32(cx[j]), mxx = wave_max_f32(cx[j]);
        float mny = wave_min_f32(cy[j]), mxy = wave_max_f32(cy[j]);
        float mnz = wave_min_f32(cz[j]), mxz = wave_max_f32(cz[j]);
        if (lane == 63) {
            s_bb[b][0] = mnx; s_bb[b][1] = mny; s_bb[b][2] = mnz;
            s_bb[b][3] = mxx; s_bb[b][4] = mxy; s_bb[b][5] = mxz;
        }
    }

    int pos0 = min(max(pos0s[batch], 0), N_IN - 1);
    const float* q0r = base + (size_t)pos0 * 3;
    float q0x = q0r[0], q0y = q0r[1], q0z = q0r[2];
    if (tid == 0) iout[0] = 0;

    double bv = -1.0;
    int    boi = 0x7FFFFFFF, bj = 0;
    float  bcx = 0.f, bcy = 0.f, bcz = 0.f;
#pragma unroll
    for (int j = 0; j < PPT; ++j) {
        md[j] = dist2d(cx[j], cy[j], cz[j], (double)q0x, (double)q0y, (double)q0z);
        th[j] = __fmul_rn((float)md[j], 1.000004f);
        if (md[j] > bv) {
            bv = md[j]; boi = oi_[j]; bj = j;
            bcx = cx[j]; bcy = cy[j]; bcz = cz[j];
        }
    }

    // one-time: thmax init
#pragma unroll
    for (int j = 0; j < PPT; ++j) {
        float t = wave_max_f32(th[j]);
        if (lane == 63) s_thmax[j * NW + wvu] = t;
    }
    __syncthreads();

    // load this lane's bucket AABB(s) into registers
    float blx[BPL], bly[BPL], blz[BPL], bhx[BPL], bhy[BPL], bhz[BPL];
#pragma unroll
    for (int k = 0; k < BPL; ++k) {
        int b = lane + k * 64;
        if (b < NB) {
            blx[k] = s_bb[b][0]; bly[k] = s_bb[b][1]; blz[k] = s_bb[b][2];
            bhx[k] = s_bb[b][3]; bhy[k] = s_bb[b][4]; bhz[k] = s_bb[b][5];
        } else {
            blx[k] = 1e30f; bly[k] = 1e30f; blz[k] = 1e30f;
            bhx[k] = -1e30f; bhy[k] = -1e30f; bhz[k] = -1e30f;
        }
    }

    unsigned dirty = 0;

    for (int i = 1; i < npoints; ++i) {
        const int par = i & 1;

        // ---- 1. wave argmax via hi-bits (md >= 0) ----
        int hb = hi32d(bv);
        int mh = __builtin_amdgcn_readlane(wave_max_i32(hb), 63);
        unsigned long long sel = __ballot(hb == mh);
        int wl;
        if (__popcll(sel) == 1) {
            wl = __ffsll(sel) - 1;
        } else {
            unsigned lb = (unsigned)lo32d(bv);
            unsigned cl = (hb == mh) ? lb : 0u;
            unsigned mlo = (unsigned)__builtin_amdgcn_readlane((int)wave_max_u32(cl), 63);
            unsigned long long sel2 = __ballot(hb == mh && lb == mlo);
            if (__popcll(sel2) == 1) {
                wl = __ffsll(sel2) - 1;
            } else {  // exact f64 tie: min original index (bounded)
                int c = (hb == mh && lb == mlo) ? boi : 0x7FFFFFFF;
                int mo = __builtin_amdgcn_readlane(wave_min_i32(c), 63);
                unsigned long long sel3 = __ballot(c == mo);
                wl = max(__ffsll(sel3) - 1, 0);
            }
        }
        if (lane == wl) {
            int4 a; a.x = lo32d(bv); a.y = hi32d(bv); a.z = boi;
            a.w = __float_as_int(bcx);
            *(int4*)&s_part[par][wvu][0] = a;
            int2 b2; b2.x = __float_as_int(bcy); b2.y = __float_as_int(bcz);
            *(int2*)&s_part[par][wvu][4] = b2;
        }
        __syncthreads();

        // thmax loads (early issue; consumed by BB gate below)
        float tm[BPL];
#pragma unroll
        for (int k = 0; k < BPL; ++k) {
            int b = lane + k * 64;
            tm[k] = (b < NB) ? __fmul_rn(s_thmax[b], 1.00002f) : 0.0f;
        }

        // ---- 2. cross-wave reduce of 4 partials ----
        const int sl = lane & 3;
        int4 pa = *(const int4*)&s_part[par][sl][0];
        int2 pb = *(const int2*)&s_part[par][sl][4];
        double pm = mk_f64(pa.x, pa.y);
        int    po = pa.z;
        float  px = __int_as_float(pa.w);
        float  py = __int_as_float(pb.x);
        float  pz = __int_as_float(pb.y);
        double v2 = (lane < 4) ? pm : -1.0;
        v2 = fmax(v2, dpp_f64_keep<0x111>(v2));
        v2 = fmax(v2, dpp_f64_keep<0x112>(v2));
        double gmax = readlane_f64(v2, 3);
        int c2 = (lane < 4 && pm == gmax) ? po : 0x7FFFFFFF;
        int c2m = min(c2, dpp_i<0x111>(c2));
        c2m = min(c2m, dpp_i<0x112>(c2m));
        int gmoi = __builtin_amdgcn_readlane(c2m, 3);
        unsigned long long sel4 = __ballot(c2 == gmoi) & 0xFULL;
        int wl2 = max(__ffsll(sel4) - 1, 0);
        float qx = readlane_f32(px, wl2);
        float qy = readlane_f32(py, wl2);
        float qz = readlane_f32(pz, wl2);
        if (tid == 0) iout[i] = min(max(gmoi, 0), N_IN - 1);

        // ---- 3. BB gate over all buckets ----
        unsigned long long mball[2];
#pragma unroll
        for (int k = 0; k < BPL; ++k) {
            float tx = fmaxf(fmaxf(blx[k] - qx, qx - bhx[k]), 0.0f);
            float ty = fmaxf(fmaxf(bly[k] - qy, qy - bhy[k]), 0.0f);
            float tz = fmaxf(fmaxf(blz[k] - qz, qz - bhz[k]), 0.0f);
            float d2 = fmaf(tx, tx, fmaf(ty, ty, tz * tz));
            mball[k] = __ballot(d2 < tm[k]);
        }
        if (BPL == 1) mball[1] = 0;

        unsigned fmask = 0;
#pragma unroll
        for (int j = 0; j < PPT; ++j) {
            constexpr int KIDX = 0;  // placeholder; real index below
            (void)KIDX;
            const unsigned long long mm = ((j * NW) < 64) ? mball[0] : mball[1];
            int bb = (j * NW + wvu) & 63;
            fmask |= (unsigned)((mm >> bb) & 1ULL) << j;
        }

        // ---- 4. fired buckets: screen + exact update + holder-gated rescan
        if (fmask) {
#pragma unroll
            for (int j = 0; j < PPT; ++j) {
                if (fmask & (1u << j)) {
                    float dx = cx[j] - qx;
                    float dy = cy[j] - qy;
                    float dz = cz[j] - qz;
                    float d32 = fmaf(dx, dx, fmaf(dy, dy, dz * dz));
                    if (__any(d32 < th[j])) {
                        double d = dist2d(cx[j], cy[j], cz[j],
                                          (double)qx, (double)qy, (double)qz);
                        md[j] = fmin(md[j], d);
                        th[j] = __fmul_rn((float)md[j], 1.000004f);
                        dirty |= 1u << j;
                    }
                }
            }
            int need = (int)((fmask >> bj) & 1);
            if (__any(need)) {
                if (need) {
                    bv = -1.0;
#pragma unroll
                    for (int j = 0; j < PPT; ++j) {
                        if (md[j] > bv) {
                            bv = md[j]; boi = oi_[j]; bj = j;
                            bcx = cx[j]; bcy = cy[j]; bcz = cz[j];
                        }
                    }
                }
            }
        }

        // lazy thmax refresh (stale-high is always valid)
        if ((i & 3) == 0 && dirty) {
#pragma unroll
            for (int j = 0; j < PPT; ++j) {
                if (dirty & (1u << j)) {
                    float t = wave_max_f32(th[j]);
                    if (lane == 63) s_thmax[j * NW + wvu] = t;
                }
            }
            dirty = 0;
        }
    }
}

// ---------------------------------------------------------------------------
// Gather + 2-layer pointwise MLP + xyz/feat concat, one kernel per level.
// ---------------------------------------------------------------------------
template <int CIN, int F, bool REPEAT>
__global__ __launch_bounds__(256) void mlp_kernel(
    const float* __restrict__ pts, int stride, int n_in,
    const int* __restrict__ idx,
    const float* __restrict__ w1, const float* __restrict__ b1,
    const float* __restrict__ w2, const float* __restrict__ b2,
    float* __restrict__ out, int np)
{
    constexpr int P    = 256 / F;
    constexpr int CINS = REPEAT ? (CIN / 2) : CIN;
    constexpr int LOGF = (F == 16) ? 4 : (F == 32) ? 5 : (F == 64) ? 6 : 7;

    __shared__ float xs[P][CINS];
    __shared__ float h[P][F];

    const int tid = threadIdx.x;
    const int pl  = tid >> LOGF;
    const int c   = tid & (F - 1);
    const int b   = blockIdx.y;
    const int pid = blockIdx.x * P + pl;

    int id = idx[(size_t)b * np + pid];
    id = min(max(id, 0), n_in - 1);       // replay-poison safety
    const float* row = pts + ((size_t)b * n_in + id) * stride;

    if (c < CINS) xs[pl][c] = row[c];
    __syncthreads();

    float acc = b1[c];
#pragma unroll
    for (int k = 0; k < CIN; ++k) {
        const int xk = REPEAT ? (k % 3) : k;
        acc = fmaf(xs[pl][xk], w1[k * F + c], acc);
    }
    h[pl][c] = fmaxf(acc, 0.0f);
    __syncthreads();

    float acc2 = b2[c];
#pragma unroll
    for (int f = 0; f < F; ++f)
        acc2 = fmaf(h[pl][f], w2[f * F + c], acc2);

    float res = (c < 3) ? xs[pl][c] : acc2;
    out[((size_t)b * np + pid) * (size_t)F + c] = res;
}

// ---------------------------------------------------------------------------
// Launch
// ---------------------------------------------------------------------------
extern "C" void kernel_launch(void* const* d_in, const int* in_sizes, int n_in_cnt,
                              void* d_out, int out_size, void* d_ws, size_t ws_size,
                              hipStream_t stream) {
    const float* scene = (const float*)d_in[0];
    const float* w1_1 = (const float*)d_in[1];
    const float* b1_1 = (const float*)d_in[2];
    const float* w2_1 = (const float*)d_in[3];
    const float* b2_1 = (const float*)d_in[4];
    const float* w1_2 = (const float*)d_in[5];
    const float* b1_2 = (const float*)d_in[6];
    const float* w2_2 = (const float*)d_in[7];
    const float* b2_2 = (const float*)d_in[8];
    const float* w1_3 = (const float*)d_in[9];
    const float* b1_3 = (const float*)d_in[10];
    const float* w2_3 = (const float*)d_in[11];
    const float* b2_3 = (const float*)d_in[12];
    const float* w1_4 = (const float*)d_in[13];
    const float* b1_4 = (const float*)d_in[14];
    const float* w2_4 = (const float*)d_in[15];
    const float* b2_4 = (const float*)d_in[16];

    float* out  = (float*)d_out;
    float* out1 = out;                 // [8][4096][16]
    float* out2 = out + 524288;        // [8][2048][32]
    float* out3 = out + 1048576;       // [8][1024][64]
    float* out4 = out + 1572864;       // [8][512][128]

    const int B = 8;

    int* p = (int*)d_ws;
    int* idx1 = p;            p += B * 4096;
    int* idx2 = p;            p += B * 2048;
    int* idx3 = p;            p += B * 1024;
    int* idx4 = p;            p += B * 512;
    int* pos01 = p;           p += B;
    int* pos02 = p;           p += B;
    int* pos03 = p;           p += B;
    int* pos04 = p;           p += B;
    float* pxyz1 = (float*)p; p += B * 8192 * 3;
    int*   poi1  = p;         p += B * 8192;
    float* pxyz2 = (float*)p; p += B * 4096 * 3;
    int*   poi2  = p;         p += B * 4096;
    float* pxyz3 = (float*)p; p += B * 2048 * 3;
    int*   poi3  = p;         p += B * 2048;
    float* pxyz4 = (float*)p; p += B * 1024 * 3;
    int*   poi4  = p;

    // Level 1: N=8192 -> 4096, cin=6 (repeat), F=16
    sort_kernel<8192, 512><<<B, 512, 0, stream>>>(scene, 3, pxyz1, poi1, pos01);
    fps_kernel<32><<<B, 256, 0, stream>>>(pxyz1, poi1, pos01, 4096, idx1);
    mlp_kernel<6, 16, true><<<dim3(256, B), 256, 0, stream>>>(
        scene, 3, 8192, idx1, w1_1, b1_1, w2_1, b2_1, out1, 4096);

    // Level 2: 4096 -> 2048, cin=16, F=32
    sort_kernel<4096, 512><<<B, 512, 0, stream>>>(out1, 16, pxyz2, poi2, pos02);
    fps_kernel<16><<<B, 256, 0, stream>>>(pxyz2, poi2, pos02, 2048, idx2);
    mlp_kernel<16, 32, false><<<dim3(256, B), 256, 0, stream>>>(
        out1, 16, 4096, idx2, w1_2, b1_2, w2_2, b2_2, out2, 2048);

    // Level 3: 2048 -> 1024, cin=32, F=64
    sort_kernel<2048, 256><<<B, 256, 0, stream>>>(out2, 32, pxyz3, poi3, pos03);
    fps_kernel<8><<<B, 256, 0, stream>>>(pxyz3, poi3, pos03, 1024, idx3);
    mlp_kernel<32, 64, false><<<dim3(256, B), 256, 0, stream>>>(
        out2, 32, 2048, idx3, w1_3, b1_3, w2_3, b2_3, out3, 1024);

    // Level 4: 1024 -> 512, cin=64, F=128
    sort_kernel<1024, 256><<<B, 256, 0, stream>>>(out3, 64, pxyz4, poi4, pos04);
    fps_kernel<4><<<B, 256, 0, stream>>>(pxyz4, poi4, pos04, 512, idx4);
    mlp_kernel<64, 128, false><<<dim3(256, B), 256, 0, stream>>>(
        out3, 64, 1024, idx4, w1_4, b1_4, w2_4, b2_4, out4, 512);
}

// Round 10
// 10564.056 us; speedup vs baseline: 1.4289x; 1.4289x over previous
//
#include <hip/hip_runtime.h>
#include <hip/hip_bf16.h>

// ---------------------------------------------------------------------------
// Strict f64 squared distance matching numpy float64:
//   d = ((dx*dx + dy*dy) + dz*dz), every op individually rounded, no FMA.
// ---------------------------------------------------------------------------
__device__ __forceinline__ double dist2d(float x, float y, float z,
                                         double px, double py, double pz) {
    double dx = __dsub_rn((double)x, px);
    double dy = __dsub_rn((double)y, py);
    double dz = __dsub_rn((double)z, pz);
    double a  = __dmul_rn(dx, dx);
    double b  = __dmul_rn(dy, dy);
    double c  = __dmul_rn(dz, dz);
    return __dadd_rn(__dadd_rn(a, b), c);
}

__device__ __forceinline__ int lo32d(double v) {
    return (int)(__double_as_longlong(v) & 0xFFFFFFFFLL);
}
__device__ __forceinline__ int hi32d(double v) {
    return (int)(((unsigned long long)__double_as_longlong(v)) >> 32);
}
__device__ __forceinline__ double mk_f64(int lo, int hi) {
    return __longlong_as_double(((long long)(unsigned)hi << 32) | (unsigned)lo);
}

template <int CTRL>
__device__ __forceinline__ int dpp_i(int v) {
    return __builtin_amdgcn_update_dpp(v, v, CTRL, 0xF, 0xF, false);
}
template <int CTRL>
__device__ __forceinline__ float dpp_f(float v) {
    return __int_as_float(
        __builtin_amdgcn_update_dpp(__float_as_int(v), __float_as_int(v),
                                    CTRL, 0xF, 0xF, false));
}
template <int CTRL>
__device__ __forceinline__ double dpp_f64_keep(double v) {
    long long b = __double_as_longlong(v);
    int lo = (int)(b & 0xFFFFFFFFLL);
    int hi = (int)(((unsigned long long)b) >> 32);
    int lo2 = __builtin_amdgcn_update_dpp(lo, lo, CTRL, 0xF, 0xF, false);
    int hi2 = __builtin_amdgcn_update_dpp(hi, hi, CTRL, 0xF, 0xF, false);
    return __longlong_as_double(((long long)(unsigned)hi2 << 32) | (unsigned)lo2);
}

// Lane 63 holds the full 64-lane reduction after these.
__device__ __forceinline__ int wave_max_i32(int v) {
    v = max(v, dpp_i<0x111>(v)); v = max(v, dpp_i<0x112>(v));
    v = max(v, dpp_i<0x114>(v)); v = max(v, dpp_i<0x118>(v));
    v = max(v, dpp_i<0x142>(v)); v = max(v, dpp_i<0x143>(v));
    return v;
}
__device__ __forceinline__ int wave_min_i32(int v) {
    v = min(v, dpp_i<0x111>(v)); v = min(v, dpp_i<0x112>(v));
    v = min(v, dpp_i<0x114>(v)); v = min(v, dpp_i<0x118>(v));
    v = min(v, dpp_i<0x142>(v)); v = min(v, dpp_i<0x143>(v));
    return v;
}
__device__ __forceinline__ unsigned wave_max_u32(unsigned v) {
    v = max(v, (unsigned)dpp_i<0x111>((int)v));
    v = max(v, (unsigned)dpp_i<0x112>((int)v));
    v = max(v, (unsigned)dpp_i<0x114>((int)v));
    v = max(v, (unsigned)dpp_i<0x118>((int)v));
    v = max(v, (unsigned)dpp_i<0x142>((int)v));
    v = max(v, (unsigned)dpp_i<0x143>((int)v));
    return v;
}
__device__ __forceinline__ float wave_max_f32(float v) {
    v = fmaxf(v, dpp_f<0x111>(v)); v = fmaxf(v, dpp_f<0x112>(v));
    v = fmaxf(v, dpp_f<0x114>(v)); v = fmaxf(v, dpp_f<0x118>(v));
    v = fmaxf(v, dpp_f<0x142>(v)); v = fmaxf(v, dpp_f<0x143>(v));
    return v;
}
__device__ __forceinline__ float wave_min_f32(float v) {
    v = fminf(v, dpp_f<0x111>(v)); v = fminf(v, dpp_f<0x112>(v));
    v = fminf(v, dpp_f<0x114>(v)); v = fminf(v, dpp_f<0x118>(v));
    v = fminf(v, dpp_f<0x142>(v)); v = fminf(v, dpp_f<0x143>(v));
    return v;
}

__device__ __forceinline__ double readlane_f64(double v, int l) {
    long long b = __double_as_longlong(v);
    int lo = __builtin_amdgcn_readlane((int)(b & 0xFFFFFFFFLL), l);
    int hi = __builtin_amdgcn_readlane((int)(((unsigned long long)b) >> 32), l);
    return __longlong_as_double(((long long)(unsigned)hi << 32) | (unsigned)lo);
}
__device__ __forceinline__ float readlane_f32(float v, int l) {
    return __int_as_float(__builtin_amdgcn_readlane(__float_as_int(v), l));
}

__device__ __forceinline__ unsigned part1by2(unsigned v) {
    v = (v * 0x00010001u) & 0xFF0000FFu;
    v = (v * 0x00000101u) & 0x0F00F00Fu;
    v = (v * 0x00000011u) & 0xC30C30C3u;
    v = (v * 0x00000005u) & 0x49249249u;
    return v;
}

// ---------------------------------------------------------------------------
// Spatial sort: one block per batch, bitonic sort of (morton18<<13 | pos).
// Hash quality affects only downstream skip efficiency, never correctness.
// ---------------------------------------------------------------------------
template <int N, int NT>
__global__ __launch_bounds__(NT) void sort_kernel(
    const float* __restrict__ pts, int stride,
    float* __restrict__ perm_xyz,
    int* __restrict__ perm_oi,
    int* __restrict__ pos0s)
{
    __shared__ unsigned arr[N];
    const int batch = blockIdx.x;
    const int tid   = threadIdx.x;
    const float* base = pts + (size_t)batch * N * stride;

    for (int p = tid; p < N; p += NT) {
        const float* r = base + (size_t)p * stride;
        unsigned xi = (unsigned)fminf(fmaxf((r[0] + 4.0f) * 8.0f, 0.0f), 63.0f);
        unsigned yi = (unsigned)fminf(fmaxf((r[1] + 4.0f) * 8.0f, 0.0f), 63.0f);
        unsigned zi = (unsigned)fminf(fmaxf((r[2] + 4.0f) * 8.0f, 0.0f), 63.0f);
        unsigned code = part1by2(xi) | (part1by2(yi) << 1) | (part1by2(zi) << 2);
        arr[p] = (code << 13) | (unsigned)p;
    }
    __syncthreads();

    for (int size = 2; size <= N; size <<= 1) {
        for (int str = size >> 1; str > 0; str >>= 1) {
            for (int t = tid; t < N / 2; t += NT) {
                int i = ((t & ~(str - 1)) << 1) | (t & (str - 1));
                unsigned a = arr[i], b = arr[i | str];
                bool up = ((i & size) == 0);
                if ((a > b) == up) { arr[i] = b; arr[i | str] = a; }
            }
            __syncthreads();
        }
    }

    for (int s = tid; s < N; s += NT) {
        int p = (int)(arr[s] & 0x1FFFu);
        const float* r = base + (size_t)p * stride;
        float* w = perm_xyz + ((size_t)batch * N + s) * 3;
        w[0] = r[0]; w[1] = r[1]; w[2] = r[2];
        perm_oi[(size_t)batch * N + s] = p;
        if (p == 0) pos0s[batch] = s;
    }
}

// ---------------------------------------------------------------------------
// FPS on Morton-sorted points. NT threads (NT/64 waves) per batch, one block
// per batch. Bucket b = j*NW + wv covers sorted positions [b*64, b*64+64);
// lane l of every wave holds the static AABB of bucket l (and l+64 if NB>64).
// Per iteration:
//   1. wave argmax via hi-bits i32 DPP (md>=0 => f64 order == (hi,lo) lex);
//      lo-bits / min-original-index fallbacks only on exact ties (bounded);
//      winning lane writes its packed partial (bv, oi, x, y, z); ONE barrier.
//   2. cross-wave reduce of NW partials (DPP f64 max + bounded min-oi tie).
//   3. BB gate: one point-to-box test per lane vs thmax[b] (LDS; monotone-
//      stale upper bound of per-point th -> conservative => exact); ballots
//      give an sgpr fire mask.
//   4. fired buckets only: per-point f32 screen (margin 1.000004, proven
//      R4-R9) gates strict-f64 md update; holder-gated rescan via the
//      iteration-local update mask; lazy thmax refresh every 4th iter.
// Register budget: PPT<=16 keeps per-lane state ~150 VGPR (no spill; the
// R9 PPT=32@256thr variant spilled to scratch -> 256 VGPR + 1GB FETCH).
// ---------------------------------------------------------------------------
template <int PPT, int NT>
__global__ __launch_bounds__(NT, (NT == 512) ? 2 : 1) void fps_kernel(
    const float* __restrict__ perm_xyz,  // [B][N_IN][3]
    const int* __restrict__ perm_oi,     // [B][N_IN]
    const int* __restrict__ pos0s,       // [B]
    int npoints,
    int* __restrict__ idx_out)           // [B][npoints] (original indices)
{
    constexpr int NW   = NT / 64;
    constexpr int N_IN = PPT * NT;
    constexpr int NB   = N_IN / 64;          // buckets
    constexpr int BPL  = (NB + 63) / 64;     // buckets per lane (1 or 2)

    const int batch = blockIdx.x;
    const int tid   = threadIdx.x;
    const int lane  = tid & 63;
    const int wvu   = __builtin_amdgcn_readfirstlane(tid >> 6);

    const float* base   = perm_xyz + (size_t)batch * N_IN * 3;
    const int*   oibase = perm_oi + (size_t)batch * N_IN;
    int* iout = idx_out + (size_t)batch * npoints;

    __shared__ int   s_part[2][NW][8];  // bv_lo, bv_hi, oi, x, y, z, pad, pad
    __shared__ float s_thmax[NB];
    __shared__ float s_bb[NB][6];

    float  cx[PPT], cy[PPT], cz[PPT];
    int    oi_[PPT];
    double md[PPT];
    float  th[PPT];

#pragma unroll
    for (int j = 0; j < PPT; ++j) {
        int s = (j * NW + wvu) * 64 + lane;
        const float* r = base + (size_t)s * 3;
        cx[j] = r[0]; cy[j] = r[1]; cz[j] = r[2];
        oi_[j] = oibase[s];
    }

    // one-time: bucket AABBs
#pragma unroll
    for (int j = 0; j < PPT; ++j) {
        int b = j * NW + wvu;
        float mnx = wave_min_f32(cx[j]), mxx = wave_max_f32(cx[j]);
        float mny = wave_min_f32(cy[j]), mxy = wave_max_f32(cy[j]);
        float mnz = wave_min_f32(cz[j]), mxz = wave_max_f32(cz[j]);
        if (lane == 63) {
            s_bb[b][0] = mnx; s_bb[b][1] = mny; s_bb[b][2] = mnz;
            s_bb[b][3] = mxx; s_bb[b][4] = mxy; s_bb[b][5] = mxz;
        }
    }

    int pos0 = min(max(pos0s[batch], 0), N_IN - 1);
    const float* q0r = base + (size_t)pos0 * 3;
    float q0x = q0r[0], q0y = q0r[1], q0z = q0r[2];
    if (tid == 0) iout[0] = 0;

    double bv = -1.0;
    int    boi = 0x7FFFFFFF, bj = 0;
    float  bcx = 0.f, bcy = 0.f, bcz = 0.f;
#pragma unroll
    for (int j = 0; j < PPT; ++j) {
        md[j] = dist2d(cx[j], cy[j], cz[j], (double)q0x, (double)q0y, (double)q0z);
        th[j] = __fmul_rn((float)md[j], 1.000004f);
        if (md[j] > bv) {
            bv = md[j]; boi = oi_[j]; bj = j;
            bcx = cx[j]; bcy = cy[j]; bcz = cz[j];
        }
    }

    // one-time: thmax init
#pragma unroll
    for (int j = 0; j < PPT; ++j) {
        float t = wave_max_f32(th[j]);
        if (lane == 63) s_thmax[j * NW + wvu] = t;
    }
    __syncthreads();

    // this lane's bucket AABB(s) into registers (static for the whole run)
    float blx[BPL], bly[BPL], blz[BPL], bhx[BPL], bhy[BPL], bhz[BPL];
#pragma unroll
    for (int k = 0; k < BPL; ++k) {
        int b = lane + k * 64;
        if (b < NB) {
            blx[k] = s_bb[b][0]; bly[k] = s_bb[b][1]; blz[k] = s_bb[b][2];
            bhx[k] = s_bb[b][3]; bhy[k] = s_bb[b][4]; bhz[k] = s_bb[b][5];
        } else {
            blx[k] = 1e30f; bly[k] = 1e30f; blz[k] = 1e30f;
            bhx[k] = -1e30f; bhy[k] = -1e30f; bhz[k] = -1e30f;
        }
    }

    unsigned dirty = 0;

    for (int i = 1; i < npoints; ++i) {
        const int par = i & 1;

        // ---- 1. wave argmax via hi-bits (md >= 0 always) ----
        int hb = hi32d(bv);
        int mh = __builtin_amdgcn_readlane(wave_max_i32(hb), 63);
        unsigned long long sel = __ballot(hb == mh);
        int wl;
        if (__popcll(sel) == 1) {
            wl = __ffsll(sel) - 1;
        } else {
            unsigned lb = (unsigned)lo32d(bv);
            unsigned cl = (hb == mh) ? lb : 0u;
            unsigned mlo = (unsigned)__builtin_amdgcn_readlane((int)wave_max_u32(cl), 63);
            unsigned long long sel2 = __ballot(hb == mh && lb == mlo);
            if (__popcll(sel2) == 1) {
                wl = __ffsll(sel2) - 1;
            } else {  // exact f64 tie: min original index (bounded)
                int c = (hb == mh && lb == mlo) ? boi : 0x7FFFFFFF;
                int mo = __builtin_amdgcn_readlane(wave_min_i32(c), 63);
                unsigned long long sel3 = __ballot(c == mo);
                wl = max(__ffsll(sel3) - 1, 0);
            }
        }
        if (lane == wl) {
            int4 a; a.x = lo32d(bv); a.y = hi32d(bv); a.z = boi;
            a.w = __float_as_int(bcx);
            *(int4*)&s_part[par][wvu][0] = a;
            int2 b2; b2.x = __float_as_int(bcy); b2.y = __float_as_int(bcz);
            *(int2*)&s_part[par][wvu][4] = b2;
        }
        __syncthreads();

        // thmax loads (early issue; consumed by the BB gate)
        float tm[BPL];
#pragma unroll
        for (int k = 0; k < BPL; ++k) {
            int b = lane + k * 64;
            tm[k] = (b < NB) ? __fmul_rn(s_thmax[b], 1.00002f) : 0.0f;
        }

        // ---- 2. cross-wave reduce of NW partials (lanes 0..NW-1) ----
        const int sl = lane & (NW - 1);
        int4 pa = *(const int4*)&s_part[par][sl][0];
        int2 pb = *(const int2*)&s_part[par][sl][4];
        double pm = mk_f64(pa.x, pa.y);
        int    po = pa.z;
        float  px = __int_as_float(pa.w);
        float  py = __int_as_float(pb.x);
        float  pz = __int_as_float(pb.y);
        double v2 = (lane < NW) ? pm : -1.0;
        v2 = fmax(v2, dpp_f64_keep<0x111>(v2));
        v2 = fmax(v2, dpp_f64_keep<0x112>(v2));
        if (NW == 8) v2 = fmax(v2, dpp_f64_keep<0x114>(v2));
        double gmax = readlane_f64(v2, NW - 1);
        int c2 = (lane < NW && pm == gmax) ? po : 0x7FFFFFFF;
        int c2m = min(c2, dpp_i<0x111>(c2));
        c2m = min(c2m, dpp_i<0x112>(c2m));
        if (NW == 8) c2m = min(c2m, dpp_i<0x114>(c2m));
        int gmoi = __builtin_amdgcn_readlane(c2m, NW - 1);
        unsigned long long sel4 = __ballot(c2 == gmoi) & ((1ULL << NW) - 1);
        int wl2 = max(__ffsll(sel4) - 1, 0);
        float qx = readlane_f32(px, wl2);
        float qy = readlane_f32(py, wl2);
        float qz = readlane_f32(pz, wl2);
        if (tid == 0) iout[i] = min(max(gmoi, 0), N_IN - 1);

        // ---- 3. BB gate: one point-to-box test per lane, all buckets ----
        unsigned long long mb[BPL];
#pragma unroll
        for (int k = 0; k < BPL; ++k) {
            float tx = fmaxf(fmaxf(blx[k] - qx, qx - bhx[k]), 0.0f);
            float ty = fmaxf(fmaxf(bly[k] - qy, qy - bhy[k]), 0.0f);
            float tz = fmaxf(fmaxf(blz[k] - qz, qz - bhz[k]), 0.0f);
            float d2 = fmaf(tx, tx, fmaf(ty, ty, tz * tz));
            mb[k] = __ballot(d2 < tm[k]);
        }

        unsigned fmask = 0;
#pragma unroll
        for (int j = 0; j < PPT; ++j) {
            const unsigned long long mm = mb[(j * NW) >> 6];
            const int bit = (j * NW + wvu) & 63;
            fmask |= (unsigned)((mm >> bit) & 1ULL) << j;
        }

        // ---- 4. fired buckets: screen + exact f64 update + rescan ----
        if (fmask) {
            unsigned updmask = 0;
#pragma unroll
            for (int j = 0; j < PPT; ++j) {
                if (fmask & (1u << j)) {
                    float dx = cx[j] - qx;
                    float dy = cy[j] - qy;
                    float dz = cz[j] - qz;
                    float d32 = fmaf(dx, dx, fmaf(dy, dy, dz * dz));
                    if (__any(d32 < th[j])) {
                        double d = dist2d(cx[j], cy[j], cz[j],
                                          (double)qx, (double)qy, (double)qz);
                        md[j] = fmin(md[j], d);    // no-op where over-fired
                        th[j] = __fmul_rn((float)md[j], 1.000004f);
                        updmask |= 1u << j;        // wave-uniform
                    }
                }
            }
            dirty |= updmask;
            int need = (int)((updmask >> bj) & 1);
            if (__any(need)) {
                if (need) {
                    bv = -1.0;
#pragma unroll
                    for (int j = 0; j < PPT; ++j) {
                        if (md[j] > bv) {
                            bv = md[j]; boi = oi_[j]; bj = j;
                            bcx = cx[j]; bcy = cy[j]; bcz = cz[j];
                        }
                    }
                }
            }
        }

        // lazy thmax refresh (stale-high is always conservative)
        if ((i & 3) == 0 && dirty) {
#pragma unroll
            for (int j = 0; j < PPT; ++j) {
                if (dirty & (1u << j)) {
                    float t = wave_max_f32(th[j]);
                    if (lane == 63) s_thmax[j * NW + wvu] = t;
                }
            }
            dirty = 0;
        }
    }
}

// ---------------------------------------------------------------------------
// Gather + 2-layer pointwise MLP + xyz/feat concat, one kernel per level.
// ---------------------------------------------------------------------------
template <int CIN, int F, bool REPEAT>
__global__ __launch_bounds__(256) void mlp_kernel(
    const float* __restrict__ pts, int stride, int n_in,
    const int* __restrict__ idx,
    const float* __restrict__ w1, const float* __restrict__ b1,
    const float* __restrict__ w2, const float* __restrict__ b2,
    float* __restrict__ out, int np)
{
    constexpr int P    = 256 / F;
    constexpr int CINS = REPEAT ? (CIN / 2) : CIN;
    constexpr int LOGF = (F == 16) ? 4 : (F == 32) ? 5 : (F == 64) ? 6 : 7;

    __shared__ float xs[P][CINS];
    __shared__ float h[P][F];

    const int tid = threadIdx.x;
    const int pl  = tid >> LOGF;
    const int c   = tid & (F - 1);
    const int b   = blockIdx.y;
    const int pid = blockIdx.x * P + pl;

    int id = idx[(size_t)b * np + pid];
    id = min(max(id, 0), n_in - 1);       // replay-poison safety
    const float* row = pts + ((size_t)b * n_in + id) * stride;

    if (c < CINS) xs[pl][c] = row[c];
    __syncthreads();

    float acc = b1[c];
#pragma unroll
    for (int k = 0; k < CIN; ++k) {
        const int xk = REPEAT ? (k % 3) : k;
        acc = fmaf(xs[pl][xk], w1[k * F + c], acc);
    }
    h[pl][c] = fmaxf(acc, 0.0f);
    __syncthreads();

    float acc2 = b2[c];
#pragma unroll
    for (int f = 0; f < F; ++f)
        acc2 = fmaf(h[pl][f], w2[f * F + c], acc2);

    float res = (c < 3) ? xs[pl][c] : acc2;
    out[((size_t)b * np + pid) * (size_t)F + c] = res;
}

// ---------------------------------------------------------------------------
// Launch
// ---------------------------------------------------------------------------
extern "C" void kernel_launch(void* const* d_in, const int* in_sizes, int n_in_cnt,
                              void* d_out, int out_size, void* d_ws, size_t ws_size,
                              hipStream_t stream) {
    const float* scene = (const float*)d_in[0];
    const float* w1_1 = (const float*)d_in[1];
    const float* b1_1 = (const float*)d_in[2];
    const float* w2_1 = (const float*)d_in[3];
    const float* b2_1 = (const float*)d_in[4];
    const float* w1_2 = (const float*)d_in[5];
    const float* b1_2 = (const float*)d_in[6];
    const float* w2_2 = (const float*)d_in[7];
    const float* b2_2 = (const float*)d_in[8];
    const float* w1_3 = (const float*)d_in[9];
    const float* b1_3 = (const float*)d_in[10];
    const float* w2_3 = (const float*)d_in[11];
    const float* b2_3 = (const float*)d_in[12];
    const float* w1_4 = (const float*)d_in[13];
    const float* b1_4 = (const float*)d_in[14];
    const float* w2_4 = (const float*)d_in[15];
    const float* b2_4 = (const float*)d_in[16];

    float* out  = (float*)d_out;
    float* out1 = out;                 // [8][4096][16]
    float* out2 = out + 524288;        // [8][2048][32]
    float* out3 = out + 1048576;       // [8][1024][64]
    float* out4 = out + 1572864;       // [8][512][128]

    const int B = 8;

    int* p = (int*)d_ws;
    int* idx1 = p;            p += B * 4096;
    int* idx2 = p;            p += B * 2048;
    int* idx3 = p;            p += B * 1024;
    int* idx4 = p;            p += B * 512;
    int* pos01 = p;           p += B;
    int* pos02 = p;           p += B;
    int* pos03 = p;           p += B;
    int* pos04 = p;           p += B;
    float* pxyz1 = (float*)p; p += B * 8192 * 3;
    int*   poi1  = p;         p += B * 8192;
    float* pxyz2 = (float*)p; p += B * 4096 * 3;
    int*   poi2  = p;         p += B * 4096;
    float* pxyz3 = (float*)p; p += B * 2048 * 3;
    int*   poi3  = p;         p += B * 2048;
    float* pxyz4 = (float*)p; p += B * 1024 * 3;
    int*   poi4  = p;

    // Level 1: N=8192 -> 4096, cin=6 (repeat), F=16
    sort_kernel<8192, 512><<<B, 512, 0, stream>>>(scene, 3, pxyz1, poi1, pos01);
    fps_kernel<16, 512><<<B, 512, 0, stream>>>(pxyz1, poi1, pos01, 4096, idx1);
    mlp_kernel<6, 16, true><<<dim3(256, B), 256, 0, stream>>>(
        scene, 3, 8192, idx1, w1_1, b1_1, w2_1, b2_1, out1, 4096);

    // Level 2: 4096 -> 2048, cin=16, F=32
    sort_kernel<4096, 512><<<B, 512, 0, stream>>>(out1, 16, pxyz2, poi2, pos02);
    fps_kernel<8, 512><<<B, 512, 0, stream>>>(pxyz2, poi2, pos02, 2048, idx2);
    mlp_kernel<16, 32, false><<<dim3(256, B), 256, 0, stream>>>(
        out1, 16, 4096, idx2, w1_2, b1_2, w2_2, b2_2, out2, 2048);

    // Level 3: 2048 -> 1024, cin=32, F=64
    sort_kernel<2048, 256><<<B, 256, 0, stream>>>(out2, 32, pxyz3, poi3, pos03);
    fps_kernel<8, 256><<<B, 256, 0, stream>>>(pxyz3, poi3, pos03, 1024, idx3);
    mlp_kernel<32, 64, false><<<dim3(256, B), 256, 0, stream>>>(
        out2, 32, 2048, idx3, w1_3, b1_3, w2_3, b2_3, out3, 1024);

    // Level 4: 1024 -> 512, cin=64, F=128
    sort_kernel<1024, 256><<<B, 256, 0, stream>>>(out3, 64, pxyz4, poi4, pos04);
    fps_kernel<4, 256><<<B, 256, 0, stream>>>(pxyz4, poi4, pos04, 512, idx4);
    mlp_kernel<64, 128, false><<<dim3(256, B), 256, 0, stream>>>(
        out3, 64, 1024, idx4, w1_4, b1_4, w2_4, b2_4, out4, 512);
}